// Round 10
// baseline (638.845 us; speedup 1.0000x reference)
//
#include <hip/hip_runtime.h>
#include <stdint.h>

#define T_STEPS 512
#define BATCH   128
#define N_IN    256
#define N_H     1024
#define N_OUT   32

// ---------------- Kernel A: compact spike indices, 16 rows per block ----------------
// pairs[row][32] u32 words, each = idx_even | idx_odd<<16 (sentinel 256 -> zero
// row in the LDS weight tile); cnts[row] = active count (<=64).
__global__ __launch_bounds__(256) void k_prep(const float* __restrict__ spikes,
                                              uint32_t* __restrict__ pairs,
                                              uint32_t* __restrict__ cnts) {
    __shared__ uint16_t list[64];
    __shared__ uint32_t wcnt[4];
    const int tid = threadIdx.x;
    const int wave = tid >> 6, lane = tid & 63;
    for (int r = 0; r < 16; ++r) {
        const int row = blockIdx.x * 16 + r;       // t*BATCH + b
        float s = spikes[(size_t)row * N_IN + tid];
        bool act = s > 0.5f;                       // spikes are exactly 0.0/1.0
        unsigned long long m = __ballot(act);
        if (tid < 64) list[tid] = 256;             // sentinel
        if (lane == 0) wcnt[wave] = (uint32_t)__popcll(m);
        __syncthreads();
        uint32_t off = 0;
        for (int w = 0; w < wave; ++w) off += wcnt[w];
        uint32_t total = wcnt[0] + wcnt[1] + wcnt[2] + wcnt[3];
        if (act) {
            uint32_t pos = off + (uint32_t)__popcll(m & ((1ull << lane) - 1ull));
            if (pos < 64) list[pos] = (uint16_t)tid;   // ascending input index order
        }
        __syncthreads();
        if (tid < 32) {
            uint32_t w = (uint32_t)list[2 * tid] | ((uint32_t)list[2 * tid + 1] << 16);
            pairs[(size_t)row * 32 + tid] = w;
        }
        if (tid == 0) cnts[row] = total < 64u ? total : 64u;
        __syncthreads();
    }
}

// ---------------- Kernel T: transpose w_h[h][i] -> w_t[i][h] ----------------
__global__ __launch_bounds__(256) void k_tr(const float* __restrict__ w_h,
                                            float* __restrict__ w_t) {
    int gid = blockIdx.x * 256 + threadIdx.x;   // 262144 elements
    int h = gid >> 8, i = gid & 255;
    w_t[(size_t)i * N_H + h] = w_h[gid];
}

// ---------------- Kernel 12: fused sparse synapse + LIF scan ----------------
// Round-10 (= round-9 design, ACC16 token-paste fixed with `P##0 .x`).
// BRANCHLESS dual-stream gather: compacted positions >= cnt hold sentinel 256
// -> sentinel LDS zero row -> +0.0f reads; x+0.0f is a bit-exact identity
// (no -0.0/NaN weights), so the cnt<=32 path needs NO guards: all 32
// ds_read_b64 of both streams issue up-front (max MLP, no branch
// serialization - r8's scalar guards kept pipes in lockstep wait-use loops
// at 49% VALUBusy). Tail (cnt>32, ~6%) stays branch-guarded. Accumulation
// order: word 0..15 then 16..31, same as r8 -> bit-identical spikes.
__global__ __launch_bounds__(512) void k_lif(const uint32_t* __restrict__ pairs,
                                             const uint32_t* __restrict__ cnts,
                                             const float* __restrict__ w_t,
                                             uint32_t* __restrict__ zmask) {
    extern __shared__ __align__(16) float wl[];   // 257*64 floats = 65,792 B
    const int bg = blockIdx.x >> 4, tile = blockIdx.x & 15;
    const int h0 = tile * 64, tid = threadIdx.x;

    #pragma unroll 8
    for (int k = 0; k < 8; ++k) {                 // 256 rows x 16 float4 = 4096
        int idx = (k << 9) + tid;
        int i = idx >> 4, c4 = (idx & 15) << 2;
        *(float4*)(wl + i * 64 + c4) =
            *(const float4*)(w_t + (size_t)i * N_H + h0 + c4);
    }
    if (tid < 64) wl[256 * 64 + tid] = 0.0f;      // sentinel row
    __syncthreads();

    const int wv = __builtin_amdgcn_readfirstlane(tid >> 6);  // uniform wave id
    const int b  = (bg << 3) + wv;                // one b per wave, uniform
    const int l  = tid & 63;
    const int duo2 = (l & 31) << 1;               // float offset of h-duo
    const uint32_t vshift = (uint32_t)((l >> 5) << 4);  // parity: 0 or 16

    uint32_t cA, cB, cC, cD;                      // scalar counts
    uint4 A0,A1,A2,A3, B0,B1,B2,B3, C0,C1,C2,C3, D0,D1,D2,D3;  // SGPR idx sets

#define LOADSET(CN, S0,S1,S2,S3, ROW) { \
    const uint4* wp = (const uint4*)(pairs + (size_t)(ROW) * 32); \
    CN = cnts[ROW]; S0 = wp[0]; S1 = wp[1]; S2 = wp[2]; S3 = wp[3]; }

#define DECL16(P) float2 P##0,P##1,P##2,P##3,P##4,P##5,P##6,P##7, \
                        P##8,P##9,P##10,P##11,P##12,P##13,P##14,P##15;
#define LD2(DST, W) { uint32_t ia_ = ((W) >> vshift) & 0xFFFFu; \
                      DST = *(const float2*)(wl + ia_ * 64 + duo2); }
#define LDALL(P, S0,S1,S2,S3) \
    LD2(P##0,(S0).x)  LD2(P##1,(S0).y)  LD2(P##2,(S0).z)  LD2(P##3,(S0).w) \
    LD2(P##4,(S1).x)  LD2(P##5,(S1).y)  LD2(P##6,(S1).z)  LD2(P##7,(S1).w) \
    LD2(P##8,(S2).x)  LD2(P##9,(S2).y)  LD2(P##10,(S2).z) LD2(P##11,(S2).w) \
    LD2(P##12,(S3).x) LD2(P##13,(S3).y) LD2(P##14,(S3).z) LD2(P##15,(S3).w)
// NOTE the space before .x/.y: `P##0.x` would paste against pp-number `0.x`.
#define ACC16(G0,G1,P) \
    G0 += P##0 .x;  G1 += P##0 .y;  G0 += P##1 .x;  G1 += P##1 .y;  \
    G0 += P##2 .x;  G1 += P##2 .y;  G0 += P##3 .x;  G1 += P##3 .y;  \
    G0 += P##4 .x;  G1 += P##4 .y;  G0 += P##5 .x;  G1 += P##5 .y;  \
    G0 += P##6 .x;  G1 += P##6 .y;  G0 += P##7 .x;  G1 += P##7 .y;  \
    G0 += P##8 .x;  G1 += P##8 .y;  G0 += P##9 .x;  G1 += P##9 .y;  \
    G0 += P##10 .x; G1 += P##10 .y; G0 += P##11 .x; G1 += P##11 .y; \
    G0 += P##12 .x; G1 += P##12 .y; G0 += P##13 .x; G1 += P##13 .y; \
    G0 += P##14 .x; G1 += P##14 .y; G0 += P##15 .x; G1 += P##15 .y;
// Tail: rare (~6%); adds words 16..31 AFTER the base 16 (same order as r8).
#define TAIL32(G0,G1, CS, ROW) if ((CS) > 32u) { \
    const uint4* wp_ = (const uint4*)(pairs + (size_t)(ROW) * 32); \
    uint4 T4_ = wp_[4], T5_ = wp_[5], T6_ = wp_[6], T7_ = wp_[7]; \
    DECL16(tu) LDALL(tu, T4_,T5_,T6_,T7_) ACC16(G0,G1,tu) }

    float v0 = 0, v1 = 0, s0 = 0, s1 = 0;
    LOADSET(cA, A0,A1,A2,A3, b);                 // idx(0)
    LOADSET(cB, B0,B1,B2,B3, BATCH + b);         // idx(1)
    LOADSET(cC, C0,C1,C2,C3, 2 * BATCH + b);     // idx(2)
    LOADSET(cD, D0,D1,D2,D3, 3 * BATCH + b);     // idx(3)

    for (int t = 0; t < T_STEPS; t += 2) {
        const int rowA = t * BATCH + b;
        const int rowB = rowA + BATCH;
        const uint32_t csA = __builtin_amdgcn_readfirstlane(cA);
        const uint32_t csB = __builtin_amdgcn_readfirstlane(cB);

        // issue ALL 32 b64 reads of both streams - zero branches in between
        DECL16(ra) DECL16(rb)
        LDALL(ra, A0,A1,A2,A3)
        LDALL(rb, B0,B1,B2,B3)

        float ca0 = 0.0f, ca1 = 0.0f, cb0 = 0.0f, cb1 = 0.0f;
        ACC16(ca0, ca1, ra)
        TAIL32(ca0, ca1, csA, rowA)

        // rotate prefetch: A<-idx(t+2), B<-idx(t+3); fetch t+4, t+5
        cA = cC; A0=C0; A1=C1; A2=C2; A3=C3;
        cB = cD; B0=D0; B1=D1; B2=D2; B3=D3;
        int r4 = t + 4; if (r4 > T_STEPS - 1) r4 = T_STEPS - 1;
        int r5 = t + 5; if (r5 > T_STEPS - 1) r5 = T_STEPS - 1;
        LOADSET(cC, C0,C1,C2,C3, r4 * BATCH + b);
        LOADSET(cD, D0,D1,D2,D3, r5 * BATCH + b);

        // ---- step t (identical math/order to rounds 1-8) ----
        ca0 += __shfl_xor(ca0, 32);
        ca1 += __shfl_xor(ca1, 32);
        s0 = __builtin_fmaf(s0, 0.875f, ca0);
        s1 = __builtin_fmaf(s1, 0.875f, ca1);
        v0 = __builtin_fmaf(0.125f, s0 - v0, v0);
        v1 = __builtin_fmaf(0.125f, s1 - v1, v1);
        unsigned long long m0 = __ballot(v0 > 1.0f);
        unsigned long long m1 = __ballot(v1 > 1.0f);
        if (v0 > 1.0f) v0 = 0.0f;
        if (v1 > 1.0f) v1 = 0.0f;
        if (l == 0) {
            uint2* zp = (uint2*)(zmask + (size_t)rowA * 32 + (tile << 1));
            *zp = make_uint2((uint32_t)m0, (uint32_t)m1);
        }

        // ---- step t+1 ----
        ACC16(cb0, cb1, rb)
        TAIL32(cb0, cb1, csB, rowB)
        cb0 += __shfl_xor(cb0, 32);
        cb1 += __shfl_xor(cb1, 32);
        s0 = __builtin_fmaf(s0, 0.875f, cb0);
        s1 = __builtin_fmaf(s1, 0.875f, cb1);
        v0 = __builtin_fmaf(0.125f, s0 - v0, v0);
        v1 = __builtin_fmaf(0.125f, s1 - v1, v1);
        m0 = __ballot(v0 > 1.0f);
        m1 = __ballot(v1 > 1.0f);
        if (v0 > 1.0f) v0 = 0.0f;
        if (v1 > 1.0f) v1 = 0.0f;
        if (l == 0) {
            uint2* zp = (uint2*)(zmask + (size_t)rowB * 32 + (tile << 1));
            *zp = make_uint2((uint32_t)m0, (uint32_t)m1);
        }
    }
#undef LOADSET
#undef DECL16
#undef LD2
#undef LDALL
#undef ACC16
#undef TAIL32
}

// ---------------- Kernel 34: output synapse + LI scan, 4-way t-split ----------------
// 2-t unroll: the two independent ctz scans and two 5-level shfl reduce
// chains interleave, halving exposed per-t reduce latency. Per-t scan &
// reduce order unchanged -> bit-identical c per t. Segment scheme as r8.
__global__ __launch_bounds__(256) void k_li(const uint32_t* __restrict__ zmask,
                                            const float* __restrict__ w_o,
                                            float* __restrict__ out,
                                            float2* __restrict__ svbuf) {
    extern __shared__ __align__(16) float wo[];   // 8 * 1025 floats = 32,800 B
    const int gb  = blockIdx.x;                   // seg(4) x b(128) x oct(4)
    const int seg = gb >> 9;
    const int rem = gb & 511;
    const int b   = rem >> 2;
    const int oct = rem & 3;
    const int o0  = oct << 3;
    const int tid = threadIdx.x;
    for (int lin = tid; lin < 8 * 1024; lin += 256) {
        int ol = lin >> 10, idx = lin & 1023;
        int word = idx >> 5, j = idx & 31;
        int h = ((word >> 1) << 6) + (j << 1) + (word & 1);  // zmask bit -> h
        wo[ol * 1025 + idx] = w_o[(size_t)(o0 + ol) * N_H + h];
    }
    __syncthreads();

    const int ol = tid >> 5, word = tid & 31;
    const float* wrow = wo + ol * 1025 + (word << 5);
    const int t0 = seg << 7, t1 = t0 + 128;

    float v = 0.0f, s = 0.0f;
    uint32_t mA = zmask[(size_t)(t0 * BATCH + b) * 32 + word];
    uint32_t mB = zmask[(size_t)((t0 + 1) * BATCH + b) * 32 + word];
    for (int t = t0; t < t1; t += 2) {
        uint32_t ma = mA, mb = mB;
        int ta = (t + 2 < t1) ? t + 2 : t;
        int tb = (t + 3 < t1) ? t + 3 : t;
        mA = zmask[(size_t)(ta * BATCH + b) * 32 + word];
        mB = zmask[(size_t)(tb * BATCH + b) * 32 + word];

        float c0 = 0.0f, c1 = 0.0f;
        while (ma) { int j = __builtin_ctz(ma); ma &= ma - 1; c0 += wrow[j]; }
        while (mb) { int j = __builtin_ctz(mb); mb &= mb - 1; c1 += wrow[j]; }

        // interleaved 5-level reductions (independent chains overlap)
        c0 += __shfl_xor(c0, 1);  c1 += __shfl_xor(c1, 1);
        c0 += __shfl_xor(c0, 2);  c1 += __shfl_xor(c1, 2);
        c0 += __shfl_xor(c0, 4);  c1 += __shfl_xor(c1, 4);
        c0 += __shfl_xor(c0, 8);  c1 += __shfl_xor(c1, 8);
        c0 += __shfl_xor(c0, 16); c1 += __shfl_xor(c1, 16);

        s = __builtin_fmaf(s, 0.875f, c0);
        v = __builtin_fmaf(0.125f, s - v, v);
        if (word == 0)
            out[(size_t)(t * BATCH + b) * 32 + o0 + ol] = v;

        s = __builtin_fmaf(s, 0.875f, c1);
        v = __builtin_fmaf(0.125f, s - v, v);
        if (word == 0)
            out[(size_t)((t + 1) * BATCH + b) * 32 + o0 + ol] = v;
    }
    if (word == 0)                        // zero-run end state of this segment
        svbuf[((size_t)seg * BATCH + b) * 32 + o0 + ol] = make_float2(s, v);
}

// ---------------- Kernel F: add homogeneous LI correction for segs 1..3 ----------------
// M^k on (i,v): i->a^k i ; v->a^k v + 0.125 k a^k i  (a = 0.875, equal
// eigenvalues). True seg start = prev zero-run ends composed through M^128.
__global__ __launch_bounds__(256) void k_fix(const float2* __restrict__ svbuf,
                                             float* __restrict__ out) {
    int idx = blockIdx.x * 256 + threadIdx.x;     // 384*128*32 elements
    int o = idx & 31;
    int r = idx >> 5;
    int b = r & 127;
    int t = 128 + (r >> 7);                       // t in [128, 512)
    int seg = t >> 7;
    int k = (t & 127) + 1;
    const float A128 = 3.7714379e-8f;             // 0.875^128
    const float C128 = 6.0343007e-7f;             // 0.125*128*A128
    float2 S = svbuf[(size_t)b * 32 + o];         // true state entering seg 1
    if (seg >= 2) {
        float2 z = svbuf[((size_t)BATCH + b) * 32 + o];
        S = make_float2(z.x + A128 * S.x, z.y + A128 * S.y + C128 * S.x);
    }
    if (seg >= 3) {
        float2 z = svbuf[((size_t)2 * BATCH + b) * 32 + o];
        S = make_float2(z.x + A128 * S.x, z.y + A128 * S.y + C128 * S.x);
    }
    float ak = exp2f((float)k * -0.19264508f);    // 0.875^k
    float corr = __builtin_fmaf(ak, S.y, 0.125f * (float)k * ak * S.x);
    out[(size_t)(t * BATCH + b) * 32 + o] += corr;
}

// ---------------- launch ----------------
extern "C" void kernel_launch(void* const* d_in, const int* in_sizes, int n_in,
                              void* d_out, int out_size, void* d_ws, size_t ws_size,
                              hipStream_t stream) {
    const float* spikes = (const float*)d_in[0];
    const float* w_h    = (const float*)d_in[1];
    const float* w_o    = (const float*)d_in[2];
    float* out = (float*)d_out;

    char* ws = (char*)d_ws;
    uint32_t* pairs = (uint32_t*)(ws);                 // 8,388,608 B (k_lif only)
    uint32_t* cnts  = (uint32_t*)(ws + 8388608);       //   262,144 B (k_lif only)
    float*    w_t   = (float*)   (ws + 8650752);       // 1,048,576 B (k_lif only)
    uint32_t* zmask = (uint32_t*)(ws + 9699328);       // 8,388,608 B
    float2*   svbuf = (float2*)  (ws);                 //   131,072 B (reuses pairs
                                                       //   region; ordered after k_lif)

    const int lds12 = (256 * 64 + 64) * 4;   // 65,792 B
    const int lds34 = 8 * 1025 * 4;          // 32,800 B
    hipFuncSetAttribute((const void*)k_lif, hipFuncAttributeMaxDynamicSharedMemorySize, lds12);
    hipFuncSetAttribute((const void*)k_li,  hipFuncAttributeMaxDynamicSharedMemorySize, lds34);

    k_prep<<<(T_STEPS * BATCH) / 16, 256, 0, stream>>>(spikes, pairs, cnts);
    k_tr<<<(N_H * N_IN) / 256, 256, 0, stream>>>(w_h, w_t);
    k_lif<<<256, 512, lds12, stream>>>(pairs, cnts, w_t, zmask);
    k_li<<<4 * BATCH * 4, 256, lds34, stream>>>(zmask, w_o, out, svbuf);
    k_fix<<<(384 * BATCH * N_OUT) / 256, 256, 0, stream>>>(svbuf, out);
}

// Round 11
// 600.621 us; speedup vs baseline: 1.0636x; 1.0636x over previous
//
#include <hip/hip_runtime.h>
#include <stdint.h>

#define T_STEPS 512
#define BATCH   128
#define N_IN    256
#define N_H     1024
#define N_OUT   32

// ---------------- Kernel A: compact spike indices, 16 rows per block ----------------
// pairs[row][32] u32 words, each = idx_even | idx_odd<<16 (sentinel 256 -> zero
// row in the LDS weight tile); cnts[row] = active count (<=64).
__global__ __launch_bounds__(256) void k_prep(const float* __restrict__ spikes,
                                              uint32_t* __restrict__ pairs,
                                              uint32_t* __restrict__ cnts) {
    __shared__ uint16_t list[64];
    __shared__ uint32_t wcnt[4];
    const int tid = threadIdx.x;
    const int wave = tid >> 6, lane = tid & 63;
    for (int r = 0; r < 16; ++r) {
        const int row = blockIdx.x * 16 + r;       // t*BATCH + b
        float s = spikes[(size_t)row * N_IN + tid];
        bool act = s > 0.5f;                       // spikes are exactly 0.0/1.0
        unsigned long long m = __ballot(act);
        if (tid < 64) list[tid] = 256;             // sentinel
        if (lane == 0) wcnt[wave] = (uint32_t)__popcll(m);
        __syncthreads();
        uint32_t off = 0;
        for (int w = 0; w < wave; ++w) off += wcnt[w];
        uint32_t total = wcnt[0] + wcnt[1] + wcnt[2] + wcnt[3];
        if (act) {
            uint32_t pos = off + (uint32_t)__popcll(m & ((1ull << lane) - 1ull));
            if (pos < 64) list[pos] = (uint16_t)tid;   // ascending input index order
        }
        __syncthreads();
        if (tid < 32) {
            uint32_t w = (uint32_t)list[2 * tid] | ((uint32_t)list[2 * tid + 1] << 16);
            pairs[(size_t)row * 32 + tid] = w;
        }
        if (tid == 0) cnts[row] = total < 64u ? total : 64u;
        __syncthreads();
    }
}

// ---------------- Kernel T: transpose w_h[h][i] -> w_t[i][h] ----------------
__global__ __launch_bounds__(256) void k_tr(const float* __restrict__ w_h,
                                            float* __restrict__ w_t) {
    int gid = blockIdx.x * 256 + threadIdx.x;   // 262144 elements
    int h = gid >> 8, i = gid & 255;
    w_t[(size_t)i * N_H + h] = w_h[gid];
}

// ---------------- Kernel 12: fused sparse synapse + LIF scan ----------------
// Round-11: r8's guarded dual-stream gather (369 us; r10's branchless was a
// measured regression - compiler re-sank loads at VGPR=36, never got the MLP)
// + GRID FIX: r10's occupancy cap was grid=256 blocks on 256 CUs = 1
// block/CU = 2 waves/SIMD, NOT resources (LDS 65.8 KB x2 fits, VGPR 36).
// Now: 4-wave blocks (256 thr, 4 b each), grid 512 -> 2 blocks/CU ->
// 16 waves/CU = 4 waves/SIMD, double TLP for the same total waves.
// Per-lane arithmetic sequence unchanged -> bit-identical spikes.
__global__ __launch_bounds__(256) void k_lif(const uint32_t* __restrict__ pairs,
                                             const uint32_t* __restrict__ cnts,
                                             const float* __restrict__ w_t,
                                             uint32_t* __restrict__ zmask) {
    extern __shared__ __align__(16) float wl[];   // 257*64 floats = 65,792 B
    const int bg = blockIdx.x >> 4, tile = blockIdx.x & 15;
    const int h0 = tile * 64, tid = threadIdx.x;

    #pragma unroll 8
    for (int k = 0; k < 16; ++k) {                // 256 rows x 16 float4 = 4096
        int idx = (k << 8) + tid;
        int i = idx >> 4, c4 = (idx & 15) << 2;
        *(float4*)(wl + i * 64 + c4) =
            *(const float4*)(w_t + (size_t)i * N_H + h0 + c4);
    }
    if (tid < 64) wl[256 * 64 + tid] = 0.0f;      // sentinel row
    __syncthreads();

    const int wv = __builtin_amdgcn_readfirstlane(tid >> 6);  // uniform wave id 0..3
    const int b  = (bg << 2) + wv;                // one b per wave, uniform
    const int l  = tid & 63;
    const int duo2 = (l & 31) << 1;               // float offset of h-duo
    const uint32_t vshift = (uint32_t)((l >> 5) << 4);  // parity: 0 or 16

    uint32_t cA, cB, cC, cD;                      // scalar counts
    uint4 A0,A1,A2,A3, B0,B1,B2,B3, C0,C1,C2,C3, D0,D1,D2,D3;  // SGPR idx sets

#define LOADSET(CN, S0,S1,S2,S3, ROW) { \
    const uint4* wp = (const uint4*)(pairs + (size_t)(ROW) * 32); \
    CN = cnts[ROW]; S0 = wp[0]; S1 = wp[1]; S2 = wp[2]; S3 = wp[3]; }

#define GCHUNK(CW) { \
    uint32_t ia0 = ((CW).x >> vshift) & 0xFFFFu; \
    uint32_t ia1 = ((CW).y >> vshift) & 0xFFFFu; \
    uint32_t ia2 = ((CW).z >> vshift) & 0xFFFFu; \
    uint32_t ia3 = ((CW).w >> vshift) & 0xFFFFu; \
    const float2 r0 = *(const float2*)(wl + ia0 * 64 + duo2); \
    const float2 r1 = *(const float2*)(wl + ia1 * 64 + duo2); \
    const float2 r2 = *(const float2*)(wl + ia2 * 64 + duo2); \
    const float2 r3 = *(const float2*)(wl + ia3 * 64 + duo2); \
    gacc0 += r0.x; gacc1 += r0.y; gacc0 += r1.x; gacc1 += r1.y; \
    gacc0 += r2.x; gacc1 += r2.y; gacc0 += r3.x; gacc1 += r3.y; }

#define GATHER(OUT0, OUT1, CN, S0,S1,S2,S3, ROW) do { \
    float gacc0 = 0.0f, gacc1 = 0.0f; \
    uint32_t cs = __builtin_amdgcn_readfirstlane(CN); \
    GCHUNK(S0) \
    if (cs >  8u) GCHUNK(S1) \
    if (cs > 16u) GCHUNK(S2) \
    if (cs > 24u) GCHUNK(S3) \
    if (cs > 32u) { /* rare (~6%) tail: reload words 16..31 */ \
        const uint4* wp = (const uint4*)(pairs + (size_t)(ROW) * 32); \
        uint4 T4 = wp[4], T5 = wp[5], T6 = wp[6], T7 = wp[7]; \
        GCHUNK(T4) \
        if (cs > 40u) GCHUNK(T5) \
        if (cs > 48u) GCHUNK(T6) \
        if (cs > 56u) GCHUNK(T7) } \
    (OUT0) = gacc0; (OUT1) = gacc1; } while (0)

    float v0 = 0, v1 = 0, s0 = 0, s1 = 0;
    LOADSET(cA, A0,A1,A2,A3, b);                 // idx(0)
    LOADSET(cB, B0,B1,B2,B3, BATCH + b);         // idx(1)
    LOADSET(cC, C0,C1,C2,C3, 2 * BATCH + b);     // idx(2)
    LOADSET(cD, D0,D1,D2,D3, 3 * BATCH + b);     // idx(3)

    for (int t = 0; t < T_STEPS; t += 2) {
        const int rowA = t * BATCH + b;
        const int rowB = rowA + BATCH;
        float ca0, ca1, cb0, cb1;
        GATHER(ca0, ca1, cA, A0,A1,A2,A3, rowA);  // two independent gather
        GATHER(cb0, cb1, cB, B0,B1,B2,B3, rowB);  // streams -> 2x MLP

        // rotate prefetch: A<-idx(t+2), B<-idx(t+3); fetch t+4, t+5
        cA = cC; A0=C0; A1=C1; A2=C2; A3=C3;
        cB = cD; B0=D0; B1=D1; B2=D2; B3=D3;
        int r4 = t + 4; if (r4 > T_STEPS - 1) r4 = T_STEPS - 1;
        int r5 = t + 5; if (r5 > T_STEPS - 1) r5 = T_STEPS - 1;
        LOADSET(cC, C0,C1,C2,C3, r4 * BATCH + b);
        LOADSET(cD, D0,D1,D2,D3, r5 * BATCH + b);

        // ---- step t (identical math/order to rounds 1-10) ----
        ca0 += __shfl_xor(ca0, 32);
        ca1 += __shfl_xor(ca1, 32);
        s0 = __builtin_fmaf(s0, 0.875f, ca0);
        s1 = __builtin_fmaf(s1, 0.875f, ca1);
        v0 = __builtin_fmaf(0.125f, s0 - v0, v0);
        v1 = __builtin_fmaf(0.125f, s1 - v1, v1);
        unsigned long long m0 = __ballot(v0 > 1.0f);
        unsigned long long m1 = __ballot(v1 > 1.0f);
        if (v0 > 1.0f) v0 = 0.0f;
        if (v1 > 1.0f) v1 = 0.0f;
        if (l == 0) {
            uint2* zp = (uint2*)(zmask + (size_t)rowA * 32 + (tile << 1));
            *zp = make_uint2((uint32_t)m0, (uint32_t)m1);
        }

        // ---- step t+1 ----
        cb0 += __shfl_xor(cb0, 32);
        cb1 += __shfl_xor(cb1, 32);
        s0 = __builtin_fmaf(s0, 0.875f, cb0);
        s1 = __builtin_fmaf(s1, 0.875f, cb1);
        v0 = __builtin_fmaf(0.125f, s0 - v0, v0);
        v1 = __builtin_fmaf(0.125f, s1 - v1, v1);
        m0 = __ballot(v0 > 1.0f);
        m1 = __ballot(v1 > 1.0f);
        if (v0 > 1.0f) v0 = 0.0f;
        if (v1 > 1.0f) v1 = 0.0f;
        if (l == 0) {
            uint2* zp = (uint2*)(zmask + (size_t)rowB * 32 + (tile << 1));
            *zp = make_uint2((uint32_t)m0, (uint32_t)m1);
        }
    }
#undef LOADSET
#undef GCHUNK
#undef GATHER
}

// ---------------- Kernel 34: output synapse + LI scan, 4-way t-split ----------------
// 2-t unroll: the two independent ctz scans and two 5-level shfl reduce
// chains interleave, halving exposed per-t reduce latency. Per-t scan &
// reduce order unchanged -> bit-identical c per t. Segment scheme as r8.
__global__ __launch_bounds__(256) void k_li(const uint32_t* __restrict__ zmask,
                                            const float* __restrict__ w_o,
                                            float* __restrict__ out,
                                            float2* __restrict__ svbuf) {
    extern __shared__ __align__(16) float wo[];   // 8 * 1025 floats = 32,800 B
    const int gb  = blockIdx.x;                   // seg(4) x b(128) x oct(4)
    const int seg = gb >> 9;
    const int rem = gb & 511;
    const int b   = rem >> 2;
    const int oct = rem & 3;
    const int o0  = oct << 3;
    const int tid = threadIdx.x;
    for (int lin = tid; lin < 8 * 1024; lin += 256) {
        int ol = lin >> 10, idx = lin & 1023;
        int word = idx >> 5, j = idx & 31;
        int h = ((word >> 1) << 6) + (j << 1) + (word & 1);  // zmask bit -> h
        wo[ol * 1025 + idx] = w_o[(size_t)(o0 + ol) * N_H + h];
    }
    __syncthreads();

    const int ol = tid >> 5, word = tid & 31;
    const float* wrow = wo + ol * 1025 + (word << 5);
    const int t0 = seg << 7, t1 = t0 + 128;

    float v = 0.0f, s = 0.0f;
    uint32_t mA = zmask[(size_t)(t0 * BATCH + b) * 32 + word];
    uint32_t mB = zmask[(size_t)((t0 + 1) * BATCH + b) * 32 + word];
    for (int t = t0; t < t1; t += 2) {
        uint32_t ma = mA, mb = mB;
        int ta = (t + 2 < t1) ? t + 2 : t;
        int tb = (t + 3 < t1) ? t + 3 : t;
        mA = zmask[(size_t)(ta * BATCH + b) * 32 + word];
        mB = zmask[(size_t)(tb * BATCH + b) * 32 + word];

        float c0 = 0.0f, c1 = 0.0f;
        while (ma) { int j = __builtin_ctz(ma); ma &= ma - 1; c0 += wrow[j]; }
        while (mb) { int j = __builtin_ctz(mb); mb &= mb - 1; c1 += wrow[j]; }

        // interleaved 5-level reductions (independent chains overlap)
        c0 += __shfl_xor(c0, 1);  c1 += __shfl_xor(c1, 1);
        c0 += __shfl_xor(c0, 2);  c1 += __shfl_xor(c1, 2);
        c0 += __shfl_xor(c0, 4);  c1 += __shfl_xor(c1, 4);
        c0 += __shfl_xor(c0, 8);  c1 += __shfl_xor(c1, 8);
        c0 += __shfl_xor(c0, 16); c1 += __shfl_xor(c1, 16);

        s = __builtin_fmaf(s, 0.875f, c0);
        v = __builtin_fmaf(0.125f, s - v, v);
        if (word == 0)
            out[(size_t)(t * BATCH + b) * 32 + o0 + ol] = v;

        s = __builtin_fmaf(s, 0.875f, c1);
        v = __builtin_fmaf(0.125f, s - v, v);
        if (word == 0)
            out[(size_t)((t + 1) * BATCH + b) * 32 + o0 + ol] = v;
    }
    if (word == 0)                        // zero-run end state of this segment
        svbuf[((size_t)seg * BATCH + b) * 32 + o0 + ol] = make_float2(s, v);
}

// ---------------- Kernel F: add homogeneous LI correction for segs 1..3 ----------------
// M^k on (i,v): i->a^k i ; v->a^k v + 0.125 k a^k i  (a = 0.875, equal
// eigenvalues). True seg start = prev zero-run ends composed through M^128.
__global__ __launch_bounds__(256) void k_fix(const float2* __restrict__ svbuf,
                                             float* __restrict__ out) {
    int idx = blockIdx.x * 256 + threadIdx.x;     // 384*128*32 elements
    int o = idx & 31;
    int r = idx >> 5;
    int b = r & 127;
    int t = 128 + (r >> 7);                       // t in [128, 512)
    int seg = t >> 7;
    int k = (t & 127) + 1;
    const float A128 = 3.7714379e-8f;             // 0.875^128
    const float C128 = 6.0343007e-7f;             // 0.125*128*A128
    float2 S = svbuf[(size_t)b * 32 + o];         // true state entering seg 1
    if (seg >= 2) {
        float2 z = svbuf[((size_t)BATCH + b) * 32 + o];
        S = make_float2(z.x + A128 * S.x, z.y + A128 * S.y + C128 * S.x);
    }
    if (seg >= 3) {
        float2 z = svbuf[((size_t)2 * BATCH + b) * 32 + o];
        S = make_float2(z.x + A128 * S.x, z.y + A128 * S.y + C128 * S.x);
    }
    float ak = exp2f((float)k * -0.19264508f);    // 0.875^k
    float corr = __builtin_fmaf(ak, S.y, 0.125f * (float)k * ak * S.x);
    out[(size_t)(t * BATCH + b) * 32 + o] += corr;
}

// ---------------- launch ----------------
extern "C" void kernel_launch(void* const* d_in, const int* in_sizes, int n_in,
                              void* d_out, int out_size, void* d_ws, size_t ws_size,
                              hipStream_t stream) {
    const float* spikes = (const float*)d_in[0];
    const float* w_h    = (const float*)d_in[1];
    const float* w_o    = (const float*)d_in[2];
    float* out = (float*)d_out;

    char* ws = (char*)d_ws;
    uint32_t* pairs = (uint32_t*)(ws);                 // 8,388,608 B (k_lif only)
    uint32_t* cnts  = (uint32_t*)(ws + 8388608);       //   262,144 B (k_lif only)
    float*    w_t   = (float*)   (ws + 8650752);       // 1,048,576 B (k_lif only)
    uint32_t* zmask = (uint32_t*)(ws + 9699328);       // 8,388,608 B
    float2*   svbuf = (float2*)  (ws);                 //   131,072 B (reuses pairs
                                                       //   region; ordered after k_lif)

    const int lds12 = (256 * 64 + 64) * 4;   // 65,792 B -> 2 blocks/CU
    const int lds34 = 8 * 1025 * 4;          // 32,800 B
    hipFuncSetAttribute((const void*)k_lif, hipFuncAttributeMaxDynamicSharedMemorySize, lds12);
    hipFuncSetAttribute((const void*)k_li,  hipFuncAttributeMaxDynamicSharedMemorySize, lds34);

    k_prep<<<(T_STEPS * BATCH) / 16, 256, 0, stream>>>(spikes, pairs, cnts);
    k_tr<<<(N_H * N_IN) / 256, 256, 0, stream>>>(w_h, w_t);
    k_lif<<<512, 256, lds12, stream>>>(pairs, cnts, w_t, zmask);
    k_li<<<4 * BATCH * 4, 256, lds34, stream>>>(zmask, w_o, out, svbuf);
    k_fix<<<(384 * BATCH * N_OUT) / 256, 256, 0, stream>>>(svbuf, out);
}